// Round 2
// baseline (13459.885 us; speedup 1.0000x reference)
//
#include <hip/hip_runtime.h>
#include <hip/hip_bf16.h>
#include <type_traits>

#define NN 50000
#define NEDGE 800000
#define HD 256
#define ACT_LD 1280
#define BN_EPS 1e-3f

using bf16 = __hip_bfloat16;

static __device__ __forceinline__ float bf2f(unsigned short u) {
    union { float f; unsigned int i; } c;
    c.i = ((unsigned int)u) << 16;
    return c.f;
}
static __device__ __forceinline__ unsigned short f2bf(float f) {
    bf16 t = __float2bfloat16(f);   // round-to-nearest-even
    return *reinterpret_cast<unsigned short*>(&t);
}

// ---------------------------------------------------------------------------
// Fused dense + batchnorm + PReLU:  out[i,j] = prelu(bn(sum_k A[i,k]*W[k,j]+b[j]))
// A: M x K row-major (lda), fp32 or bf16. W: K x 256 fp32. out: bf16 (ldo).
// 64x64 tile, 256 threads, 4x4 fp32 accum per thread.
// ---------------------------------------------------------------------------
template <typename AT>
__global__ __launch_bounds__(256)
void dense_bn_act(const AT* __restrict__ A, int lda,
                  const float* __restrict__ W,
                  const float* __restrict__ bias,
                  const float* __restrict__ bn,     // [4][256] gamma,beta,mean,var
                  const float* __restrict__ alpha,  // [256] prelu slope (may be null)
                  bf16* __restrict__ out, int ldo,
                  int M, int K)
{
    __shared__ float As[16][65];
    __shared__ float Bs[16][65];

    const int tid = threadIdx.x;
    const int tx  = tid & 15;
    const int ty  = tid >> 4;
    const int m0  = blockIdx.x * 64;
    const int n0  = blockIdx.y * 64;

    const int lr = tid >> 2;          // A row 0..63
    const int lk = (tid & 3) * 4;     // A k offset 0,4,8,12
    const int bk = tid >> 4;          // W k row 0..15
    const int bc = (tid & 15) * 4;    // W col 0..60

    float acc[4][4] = {};

    for (int k0 = 0; k0 < K; k0 += 16) {
        float4 av = make_float4(0.f, 0.f, 0.f, 0.f);
        if (m0 + lr < M) {
            if constexpr (std::is_same<AT, float>::value) {
                av = *reinterpret_cast<const float4*>(A + (size_t)(m0 + lr) * lda + k0 + lk);
            } else {
                const ushort4 u = *reinterpret_cast<const ushort4*>(A + (size_t)(m0 + lr) * lda + k0 + lk);
                av.x = bf2f(u.x); av.y = bf2f(u.y); av.z = bf2f(u.z); av.w = bf2f(u.w);
            }
        }
        const float4 bv = *reinterpret_cast<const float4*>(W + (size_t)(k0 + bk) * HD + n0 + bc);

        __syncthreads();
        As[lk + 0][lr] = av.x;
        As[lk + 1][lr] = av.y;
        As[lk + 2][lr] = av.z;
        As[lk + 3][lr] = av.w;
        Bs[bk][bc + 0] = bv.x;
        Bs[bk][bc + 1] = bv.y;
        Bs[bk][bc + 2] = bv.z;
        Bs[bk][bc + 3] = bv.w;
        __syncthreads();

#pragma unroll
        for (int kk = 0; kk < 16; ++kk) {
            float a[4], b[4];
#pragma unroll
            for (int i = 0; i < 4; ++i) a[i] = As[kk][ty * 4 + i];
#pragma unroll
            for (int j = 0; j < 4; ++j) b[j] = Bs[kk][tx * 4 + j];
#pragma unroll
            for (int i = 0; i < 4; ++i)
#pragma unroll
                for (int j = 0; j < 4; ++j)
                    acc[i][j] += a[i] * b[j];
        }
    }

    float scale[4], shift[4], al[4];
#pragma unroll
    for (int j = 0; j < 4; ++j) {
        const int c = n0 + tx * 4 + j;
        const float g  = bn[c];
        const float be = bn[HD + c];
        const float mu = bn[2 * HD + c];
        const float va = bn[3 * HD + c];
        scale[j] = g * rsqrtf(va + BN_EPS);
        shift[j] = be + (bias[c] - mu) * scale[j];
        al[j]    = alpha ? alpha[c] : 1.0f;
    }

#pragma unroll
    for (int i = 0; i < 4; ++i) {
        const int r = m0 + ty * 4 + i;
        if (r >= M) continue;
        ushort4 o;
        unsigned short* po = &o.x;
#pragma unroll
        for (int j = 0; j < 4; ++j) {
            float v = acc[i][j] * scale[j] + shift[j];
            if (alpha) v = (v >= 0.f) ? v : al[j] * v;
            po[j] = f2bf(v);
        }
        *reinterpret_cast<ushort4*>(out + (size_t)r * ldo + n0 + tx * 4) = o;
    }
}

// ---------------------------------------------------------------------------
// Edge scatter: zacc[tgt[e], :] += h[src[e], :]   (h bf16 N x 256, zacc fp32 N x 256)
// One wave per edge, 4 elems per lane, fp32 atomics.
// ---------------------------------------------------------------------------
__global__ __launch_bounds__(256)
void scatter_edges(const bf16* __restrict__ h,
                   const int* __restrict__ edge,  // [E][2] = (tgt, src)
                   float* __restrict__ zacc)
{
    const int e = blockIdx.x * 4 + (threadIdx.x >> 6);
    if (e >= NEDGE) return;
    const int lane = threadIdx.x & 63;
    const int tgt = edge[2 * e + 0];
    const int src = edge[2 * e + 1];
    const ushort4 u = *reinterpret_cast<const ushort4*>(h + (size_t)src * HD + lane * 4);
    float* zp = zacc + (size_t)tgt * HD + lane * 4;
    atomicAdd(zp + 0, bf2f(u.x));
    atomicAdd(zp + 1, bf2f(u.y));
    atomicAdd(zp + 2, bf2f(u.z));
    atomicAdd(zp + 3, bf2f(u.w));
}

// ---------------------------------------------------------------------------
// Convert fp32 zacc (N x 256) into a bf16 column block of act (ld ACT_LD).
// ---------------------------------------------------------------------------
__global__ __launch_bounds__(256)
void z_to_act(const float* __restrict__ zacc, bf16* __restrict__ dst)
{
    const int i = blockIdx.x * blockDim.x + threadIdx.x;   // over NN*64
    if (i >= NN * 64) return;
    const int n  = i >> 6;
    const int c4 = (i & 63) * 4;
    const float4 v = *reinterpret_cast<const float4*>(zacc + (size_t)n * HD + c4);
    ushort4 o;
    o.x = f2bf(v.x); o.y = f2bf(v.y); o.z = f2bf(v.z); o.w = f2bf(v.w);
    *reinterpret_cast<ushort4*>(dst + (size_t)n * ACT_LD + c4) = o;
}

// ---------------------------------------------------------------------------
// post1 (256->1 dense + bn, no act) fused with graph segment-sum.
// ---------------------------------------------------------------------------
__global__ __launch_bounds__(256)
void post1_segsum(const bf16* __restrict__ h,    // N x 256 bf16
                  const float* __restrict__ W,   // 256 x 1
                  const float* __restrict__ b,
                  const float* __restrict__ bn,  // 4 x 1
                  const int* __restrict__ seg,
                  float* __restrict__ outg)
{
    const int row = blockIdx.x * 4 + (threadIdx.x >> 6);
    const int lane = threadIdx.x & 63;
    float s = 0.f;
    if (row < NN) {
        const ushort4 u = *reinterpret_cast<const ushort4*>(h + (size_t)row * HD + lane * 4);
        const float4 wv = *reinterpret_cast<const float4*>(W + lane * 4);
        s = bf2f(u.x) * wv.x + bf2f(u.y) * wv.y + bf2f(u.z) * wv.z + bf2f(u.w) * wv.w;
    }
#pragma unroll
    for (int off = 32; off > 0; off >>= 1) s += __shfl_down(s, off);
    if (lane == 0 && row < NN) {
        const float g = bn[0], be = bn[1], mu = bn[2], va = bn[3];
        const float y = g * (s + b[0] - mu) * rsqrtf(va + BN_EPS) + be;
        atomicAdd(&outg[seg[row]], y);
    }
}

// ---------------------------------------------------------------------------
extern "C" void kernel_launch(void* const* d_in, const int* in_sizes, int n_in,
                              void* d_out, int out_size, void* d_ws, size_t ws_size,
                              hipStream_t stream)
{
    const float* x    = (const float*)d_in[0];
    const int*   edge = (const int*)d_in[1];
    const int*   seg  = (const int*)d_in[2];

    const float* Wt[7], *bi[7], *bnp[7], *ap[7];
    for (int L = 0; L < 7; ++L) {
        Wt[L]  = (const float*)d_in[4 + 4 * L + 0];
        bi[L]  = (const float*)d_in[4 + 4 * L + 1];
        bnp[L] = (const float*)d_in[4 + 4 * L + 2];
        ap[L]  = (const float*)d_in[4 + 4 * L + 3];
    }
    const float* post1_W  = (const float*)d_in[32];
    const float* post1_b  = (const float*)d_in[33];
    const float* post1_bn = (const float*)d_in[34];

    // Workspace layout (204.8 MB total):
    //   act  : bf16 N x 1280  (cols [768-256L,1024-256L) = z_L, cols [1024,1280) = out1)
    //   h    : bf16 N x 256   (per-layer dense output)
    //   zacc : fp32 N x 256   (scatter accumulator, reused per g-layer)
    bf16*  act  = (bf16*)d_ws;                                // 128.0 MB
    bf16*  h    = act + (size_t)NN * ACT_LD;                  //  25.6 MB
    float* zacc = (float*)(h + (size_t)NN * HD);              //  51.2 MB

    hipMemsetAsync(d_out, 0, (size_t)out_size * sizeof(float), stream);

    const dim3 blk(256);
    const dim3 gemm_grid((NN + 63) / 64, 4);
    const int  scat_grid = (NEDGE + 3) / 4;
    const int  conv_grid = (NN * 64 + 255) / 256;

    // pre0: x(fp32, K=128) -> h
    dense_bn_act<float><<<gemm_grid, blk, 0, stream>>>(x, 128, Wt[0], bi[0], bnp[0], ap[0], h, HD, NN, 128);
    // pre1: h(K=256) -> act[:,1024:1280) (= out1)
    dense_bn_act<bf16><<<gemm_grid, blk, 0, stream>>>(h, HD, Wt[1], bi[1], bnp[1], ap[1], act + 1024, ACT_LD, NN, 256);

    // gconv layers: input = act cols [1024-256L, 1280), K = 256*(L+1)
    for (int L = 0; L < 4; ++L) {
        const int in_off = 1024 - 256 * L;
        const int K      = 256 * (L + 1);
        dense_bn_act<bf16><<<gemm_grid, blk, 0, stream>>>(act + in_off, ACT_LD, Wt[2 + L], bi[2 + L], bnp[2 + L], ap[2 + L], h, HD, NN, K);
        hipMemsetAsync(zacc, 0, (size_t)NN * HD * sizeof(float), stream);
        scatter_edges<<<scat_grid, blk, 0, stream>>>(h, edge, zacc);
        z_to_act<<<conv_grid, blk, 0, stream>>>(zacc, act + (in_off - 256));
    }

    // post0: act(K=1280) -> h
    dense_bn_act<bf16><<<gemm_grid, blk, 0, stream>>>(act, ACT_LD, Wt[6], bi[6], bnp[6], ap[6], h, HD, NN, 1280);
    // post1 + segment-sum -> d_out (64 floats)
    post1_segsum<<<(NN + 3) / 4, blk, 0, stream>>>(h, post1_W, post1_b, post1_bn, seg, (float*)d_out);
}

// Round 3
// 3163.620 us; speedup vs baseline: 4.2546x; 4.2546x over previous
//
#include <hip/hip_runtime.h>
#include <hip/hip_bf16.h>
#include <type_traits>

#define NN 50000
#define NEDGE 800000
#define HD 256
#define ACT_LD 1280
#define BN_EPS 1e-3f

using bf16 = __hip_bfloat16;

static __device__ __forceinline__ float bf2f(unsigned short u) {
    union { float f; unsigned int i; } c;
    c.i = ((unsigned int)u) << 16;
    return c.f;
}
static __device__ __forceinline__ unsigned short f2bf(float f) {
    bf16 t = __float2bfloat16(f);   // round-to-nearest-even
    return *reinterpret_cast<unsigned short*>(&t);
}

// ---------------------------------------------------------------------------
// Fused dense + batchnorm + PReLU:  out[i,j] = prelu(bn(sum_k A[i,k]*W[k,j]+b[j]))
// A: M x K row-major (lda), fp32 or bf16. W: K x 256 fp32. out: bf16 (ldo).
// 64x64 tile, 256 threads, 4x4 fp32 accum per thread.
// ---------------------------------------------------------------------------
template <typename AT>
__global__ __launch_bounds__(256)
void dense_bn_act(const AT* __restrict__ A, int lda,
                  const float* __restrict__ W,
                  const float* __restrict__ bias,
                  const float* __restrict__ bn,     // [4][256] gamma,beta,mean,var
                  const float* __restrict__ alpha,  // [256] prelu slope (may be null)
                  bf16* __restrict__ out, int ldo,
                  int M, int K)
{
    __shared__ float As[16][65];
    __shared__ float Bs[16][65];

    const int tid = threadIdx.x;
    const int tx  = tid & 15;
    const int ty  = tid >> 4;
    const int m0  = blockIdx.x * 64;
    const int n0  = blockIdx.y * 64;

    const int lr = tid >> 2;          // A row 0..63
    const int lk = (tid & 3) * 4;     // A k offset 0,4,8,12
    const int bk = tid >> 4;          // W k row 0..15
    const int bc = (tid & 15) * 4;    // W col 0..60

    float acc[4][4] = {};

    for (int k0 = 0; k0 < K; k0 += 16) {
        float4 av = make_float4(0.f, 0.f, 0.f, 0.f);
        if (m0 + lr < M) {
            if constexpr (std::is_same<AT, float>::value) {
                av = *reinterpret_cast<const float4*>(A + (size_t)(m0 + lr) * lda + k0 + lk);
            } else {
                const ushort4 u = *reinterpret_cast<const ushort4*>(A + (size_t)(m0 + lr) * lda + k0 + lk);
                av.x = bf2f(u.x); av.y = bf2f(u.y); av.z = bf2f(u.z); av.w = bf2f(u.w);
            }
        }
        const float4 bv = *reinterpret_cast<const float4*>(W + (size_t)(k0 + bk) * HD + n0 + bc);

        __syncthreads();
        As[lk + 0][lr] = av.x;
        As[lk + 1][lr] = av.y;
        As[lk + 2][lr] = av.z;
        As[lk + 3][lr] = av.w;
        Bs[bk][bc + 0] = bv.x;
        Bs[bk][bc + 1] = bv.y;
        Bs[bk][bc + 2] = bv.z;
        Bs[bk][bc + 3] = bv.w;
        __syncthreads();

#pragma unroll
        for (int kk = 0; kk < 16; ++kk) {
            float a[4], b[4];
#pragma unroll
            for (int i = 0; i < 4; ++i) a[i] = As[kk][ty * 4 + i];
#pragma unroll
            for (int j = 0; j < 4; ++j) b[j] = Bs[kk][tx * 4 + j];
#pragma unroll
            for (int i = 0; i < 4; ++i)
#pragma unroll
                for (int j = 0; j < 4; ++j)
                    acc[i][j] += a[i] * b[j];
        }
    }

    float scale[4], shift[4], al[4];
#pragma unroll
    for (int j = 0; j < 4; ++j) {
        const int c = n0 + tx * 4 + j;
        const float g  = bn[c];
        const float be = bn[HD + c];
        const float mu = bn[2 * HD + c];
        const float va = bn[3 * HD + c];
        scale[j] = g * rsqrtf(va + BN_EPS);
        shift[j] = be + (bias[c] - mu) * scale[j];
        al[j]    = alpha ? alpha[c] : 1.0f;
    }

#pragma unroll
    for (int i = 0; i < 4; ++i) {
        const int r = m0 + ty * 4 + i;
        if (r >= M) continue;
        ushort4 o;
        unsigned short* po = &o.x;
#pragma unroll
        for (int j = 0; j < 4; ++j) {
            float v = acc[i][j] * scale[j] + shift[j];
            if (alpha) v = (v >= 0.f) ? v : al[j] * v;
            po[j] = f2bf(v);
        }
        *reinterpret_cast<ushort4*>(out + (size_t)r * ldo + n0 + tx * 4) = o;
    }
}

// ---------------------------------------------------------------------------
// CSR build: histogram of tgt, exclusive scan, fill edge list.
// ---------------------------------------------------------------------------
__global__ __launch_bounds__(256)
void hist_tgt(const int* __restrict__ edge, int* __restrict__ ecnt)
{
    const int e = blockIdx.x * blockDim.x + threadIdx.x;
    if (e >= NEDGE) return;
    atomicAdd(&ecnt[edge[2 * e]], 1);
}

__global__ __launch_bounds__(1024)
void scan_counts(const int* __restrict__ ecnt,
                 int* __restrict__ off, int* __restrict__ cursor)
{
    __shared__ int part[1024];
    const int t = threadIdx.x;
    const int CH = (NN + 1023) / 1024;   // 49
    const int base = t * CH;

    int s = 0;
    for (int i = 0; i < CH; ++i) {
        const int idx = base + i;
        if (idx < NN) s += ecnt[idx];
    }
    part[t] = s;
    __syncthreads();
    // Hillis-Steele inclusive scan over 1024 partials
    for (int d = 1; d < 1024; d <<= 1) {
        const int v = (t >= d) ? part[t - d] : 0;
        __syncthreads();
        part[t] += v;
        __syncthreads();
    }
    int running = (t == 0) ? 0 : part[t - 1];   // exclusive chunk offset
    for (int i = 0; i < CH; ++i) {
        const int idx = base + i;
        if (idx < NN) {
            off[idx] = running;
            cursor[idx] = running;
            running += ecnt[idx];
        }
    }
    if (t == 1023) off[NN] = part[1023];   // total = NEDGE
}

__global__ __launch_bounds__(256)
void fill_elist(const int* __restrict__ edge,
                int* __restrict__ cursor, int* __restrict__ elist)
{
    const int e = blockIdx.x * blockDim.x + threadIdx.x;
    if (e >= NEDGE) return;
    const int tgt = edge[2 * e + 0];
    const int src = edge[2 * e + 1];
    const int pos = atomicAdd(&cursor[tgt], 1);
    elist[pos] = src;
}

// ---------------------------------------------------------------------------
// Atomic-free gather: dst[n,:] = sum_{j in off[n]..off[n+1]} h[elist[j],:]
// One wave per node; lane handles 4 bf16 columns; fp32 register accum.
// dst is an act column block (leading dim ACT_LD), written as bf16.
// ---------------------------------------------------------------------------
__global__ __launch_bounds__(256)
void gather_nodes(const bf16* __restrict__ h,
                  const int* __restrict__ off,
                  const int* __restrict__ elist,
                  bf16* __restrict__ dst)
{
    const int node = blockIdx.x * 4 + (threadIdx.x >> 6);
    if (node >= NN) return;
    const int lane = threadIdx.x & 63;
    const int j0 = off[node];
    const int j1 = off[node + 1];

    float4 acc = make_float4(0.f, 0.f, 0.f, 0.f);
    for (int j = j0; j < j1; ++j) {
        const int src = elist[j];
        const ushort4 u = *reinterpret_cast<const ushort4*>(h + (size_t)src * HD + lane * 4);
        acc.x += bf2f(u.x);
        acc.y += bf2f(u.y);
        acc.z += bf2f(u.z);
        acc.w += bf2f(u.w);
    }
    ushort4 o;
    o.x = f2bf(acc.x); o.y = f2bf(acc.y); o.z = f2bf(acc.z); o.w = f2bf(acc.w);
    *reinterpret_cast<ushort4*>(dst + (size_t)node * ACT_LD + lane * 4) = o;
}

// ---------------------------------------------------------------------------
// post1 (256->1 dense + bn, no act) fused with graph segment-sum.
// ---------------------------------------------------------------------------
__global__ __launch_bounds__(256)
void post1_segsum(const bf16* __restrict__ h,    // N x 256 bf16
                  const float* __restrict__ W,   // 256 x 1
                  const float* __restrict__ b,
                  const float* __restrict__ bn,  // 4 x 1
                  const int* __restrict__ seg,
                  float* __restrict__ outg)
{
    const int row = blockIdx.x * 4 + (threadIdx.x >> 6);
    const int lane = threadIdx.x & 63;
    float s = 0.f;
    if (row < NN) {
        const ushort4 u = *reinterpret_cast<const ushort4*>(h + (size_t)row * HD + lane * 4);
        const float4 wv = *reinterpret_cast<const float4*>(W + lane * 4);
        s = bf2f(u.x) * wv.x + bf2f(u.y) * wv.y + bf2f(u.z) * wv.z + bf2f(u.w) * wv.w;
    }
#pragma unroll
    for (int off = 32; off > 0; off >>= 1) s += __shfl_down(s, off);
    if (lane == 0 && row < NN) {
        const float g = bn[0], be = bn[1], mu = bn[2], va = bn[3];
        const float y = g * (s + b[0] - mu) * rsqrtf(va + BN_EPS) + be;
        atomicAdd(&outg[seg[row]], y);
    }
}

// ---------------------------------------------------------------------------
extern "C" void kernel_launch(void* const* d_in, const int* in_sizes, int n_in,
                              void* d_out, int out_size, void* d_ws, size_t ws_size,
                              hipStream_t stream)
{
    const float* x    = (const float*)d_in[0];
    const int*   edge = (const int*)d_in[1];
    const int*   seg  = (const int*)d_in[2];

    const float* Wt[7], *bi[7], *bnp[7], *ap[7];
    for (int L = 0; L < 7; ++L) {
        Wt[L]  = (const float*)d_in[4 + 4 * L + 0];
        bi[L]  = (const float*)d_in[4 + 4 * L + 1];
        bnp[L] = (const float*)d_in[4 + 4 * L + 2];
        ap[L]  = (const float*)d_in[4 + 4 * L + 3];
    }
    const float* post1_W  = (const float*)d_in[32];
    const float* post1_b  = (const float*)d_in[33];
    const float* post1_bn = (const float*)d_in[34];

    // Workspace layout (~157.5 MB):
    //   act   : bf16 N x 1280 (cols [768-256L,1024-256L) = z_L, [1024,1280) = out1)
    //   h     : bf16 N x 256
    //   ecnt  : int N      (in-degree histogram)
    //   off   : int N+1    (CSR row offsets)
    //   cursor: int N      (fill cursors)
    //   elist : int NEDGE  (src node per CSR slot)
    bf16* act    = (bf16*)d_ws;                        // 128.0 MB
    bf16* h      = act + (size_t)NN * ACT_LD;          //  25.6 MB
    int*  ecnt   = (int*)(h + (size_t)NN * HD);
    int*  off    = ecnt + NN;
    int*  cursor = off + NN + 1;
    int*  elist  = cursor + NN;

    hipMemsetAsync(d_out, 0, (size_t)out_size * sizeof(float), stream);
    hipMemsetAsync(ecnt, 0, NN * sizeof(int), stream);

    const dim3 blk(256);
    const dim3 gemm_grid((NN + 63) / 64, 4);
    const int  edge_grid = (NEDGE + 255) / 256;
    const int  node_grid = (NN + 3) / 4;

    // CSR build (edge list is reused by all 4 gconv layers)
    hist_tgt<<<edge_grid, blk, 0, stream>>>(edge, ecnt);
    scan_counts<<<1, 1024, 0, stream>>>(ecnt, off, cursor);
    fill_elist<<<edge_grid, blk, 0, stream>>>(edge, cursor, elist);

    // pre0: x(fp32, K=128) -> h
    dense_bn_act<float><<<gemm_grid, blk, 0, stream>>>(x, 128, Wt[0], bi[0], bnp[0], ap[0], h, HD, NN, 128);
    // pre1: h(K=256) -> act[:,1024:1280) (= out1)
    dense_bn_act<bf16><<<gemm_grid, blk, 0, stream>>>(h, HD, Wt[1], bi[1], bnp[1], ap[1], act + 1024, ACT_LD, NN, 256);

    // gconv layers: input = act cols [1024-256L, 1280), K = 256*(L+1)
    for (int L = 0; L < 4; ++L) {
        const int in_off = 1024 - 256 * L;
        const int K      = 256 * (L + 1);
        dense_bn_act<bf16><<<gemm_grid, blk, 0, stream>>>(act + in_off, ACT_LD, Wt[2 + L], bi[2 + L], bnp[2 + L], ap[2 + L], h, HD, NN, K);
        gather_nodes<<<node_grid, blk, 0, stream>>>(h, off, elist, act + (in_off - 256));
    }

    // post0: act(K=1280) -> h
    dense_bn_act<bf16><<<gemm_grid, blk, 0, stream>>>(act, Wt[6] ? ACT_LD : ACT_LD, Wt[6], bi[6], bnp[6], ap[6], h, HD, NN, 1280);
    // post1 + segment-sum -> d_out (64 floats)
    post1_segsum<<<(NN + 3) / 4, blk, 0, stream>>>(h, post1_W, post1_b, post1_bn, seg, (float*)d_out);
}

// Round 4
// 1302.863 us; speedup vs baseline: 10.3310x; 2.4282x over previous
//
#include <hip/hip_runtime.h>
#include <hip/hip_bf16.h>

#define NN 50000
#define NEDGE 800000
#define HD 256
#define ACT_LD 1280
#define BN_EPS 1e-3f

#define BM 128
#define BN 128
#define BK 64
#define LDS_K 72   // shorts per LDS row: 64 data + 8 pad (144 B) -> full bank spread

using bf16 = __hip_bfloat16;
typedef __attribute__((ext_vector_type(8))) short bf16x8;  // 8 bf16 = 4 VGPR (MFMA A/B frag)
typedef __attribute__((ext_vector_type(4))) float f32x4;   // MFMA C/D frag

static __device__ __forceinline__ float bf2f(unsigned short u) {
    union { float f; unsigned int i; } c;
    c.i = ((unsigned int)u) << 16;
    return c.f;
}
static __device__ __forceinline__ unsigned short f2bf(float f) {
    bf16 t = __float2bfloat16(f);   // round-to-nearest-even
    return *reinterpret_cast<unsigned short*>(&t);
}

// ---------------------------------------------------------------------------
// W (K x 256 fp32, row-major) -> Wt (256 x K bf16, row-major)  [32x32 LDS tiles]
// ---------------------------------------------------------------------------
__global__ __launch_bounds__(256)
void transpose_w(const float* __restrict__ W, bf16* __restrict__ Wt, int K)
{
    __shared__ unsigned short T[32][33];
    const int k0 = blockIdx.x * 32;
    const int n0 = blockIdx.y * 32;
#pragma unroll
    for (int i = 0; i < 4; ++i) {
        const int idx = threadIdx.x + i * 256;
        const int kk = idx >> 5, nn = idx & 31;
        T[kk][nn] = f2bf(W[(size_t)(k0 + kk) * HD + n0 + nn]);
    }
    __syncthreads();
#pragma unroll
    for (int i = 0; i < 4; ++i) {
        const int idx = threadIdx.x + i * 256;
        const int nn = idx >> 5, kk = idx & 31;
        unsigned short v = T[kk][nn];
        Wt[(size_t)(n0 + nn) * K + k0 + kk] = *reinterpret_cast<bf16*>(&v);
    }
}

// ---------------------------------------------------------------------------
// x (N x 128 fp32) -> xb (N x 128 bf16)
// ---------------------------------------------------------------------------
__global__ __launch_bounds__(256)
void convert_x(const float* __restrict__ x, bf16* __restrict__ xb)
{
    const int i = blockIdx.x * blockDim.x + threadIdx.x;   // over NN*32 float4s
    if (i >= NN * 32) return;
    const float4 v = *reinterpret_cast<const float4*>(x + (size_t)i * 4);
    ushort4 o;
    o.x = f2bf(v.x); o.y = f2bf(v.y); o.z = f2bf(v.z); o.w = f2bf(v.w);
    *reinterpret_cast<ushort4*>((unsigned short*)xb + (size_t)i * 4) = o;
}

// ---------------------------------------------------------------------------
// MFMA GEMM + BN + PReLU:  out = prelu(bn(A @ W + b))
// A: M x K bf16 (lda), Wt: 256 x K bf16 (W transposed), out: bf16 (ldo).
// 128x128 tile, 4 waves (2x2), each wave 64x64 = 4x4 frags of 16x16x32.
// ---------------------------------------------------------------------------
__global__ __launch_bounds__(256)
void gemm_bn_act(const bf16* __restrict__ A, int lda,
                 const bf16* __restrict__ Wt, int K,
                 const float* __restrict__ bias,
                 const float* __restrict__ bn,
                 const float* __restrict__ alpha,
                 bf16* __restrict__ out, int ldo, int M)
{
    __shared__ short As[BM * LDS_K];
    __shared__ short Bs[BN * LDS_K];

    const int tid  = threadIdx.x;
    const int wid  = tid >> 6;
    const int lane = tid & 63;
    const int lo   = lane & 15;
    const int hi   = lane >> 4;
    const int wr   = wid >> 1;    // wave row 0..1
    const int wc   = wid & 1;     // wave col 0..1

    const int m0 = blockIdx.x * BM;
    const int n0 = blockIdx.y * BN;

    f32x4 acc[4][4] = {};   // [row-tile][col-tile]

    for (int k0 = 0; k0 < K; k0 += BK) {
        __syncthreads();
#pragma unroll
        for (int i = 0; i < 4; ++i) {
            const int ch  = tid + i * 256;     // 0..1023 : 16B chunks of the 128x64 tile
            const int row = ch >> 3;           // 0..127
            const int kc  = ch & 7;            // 8 x 16B per row
            uint4 av = make_uint4(0u, 0u, 0u, 0u);
            if (m0 + row < M)
                av = *reinterpret_cast<const uint4*>(A + (size_t)(m0 + row) * lda + k0 + kc * 8);
            *reinterpret_cast<uint4*>(&As[row * LDS_K + kc * 8]) = av;
            const uint4 bv = *reinterpret_cast<const uint4*>(Wt + (size_t)(n0 + row) * K + k0 + kc * 8);
            *reinterpret_cast<uint4*>(&Bs[row * LDS_K + kc * 8]) = bv;
        }
        __syncthreads();

#pragma unroll
        for (int kc = 0; kc < 2; ++kc) {       // two K=32 chunks
            bf16x8 af[4], bf[4];
#pragma unroll
            for (int rt = 0; rt < 4; ++rt)
                af[rt] = *reinterpret_cast<const bf16x8*>(&As[(wr * 64 + rt * 16 + lo) * LDS_K + kc * 32 + hi * 8]);
#pragma unroll
            for (int ct = 0; ct < 4; ++ct)
                bf[ct] = *reinterpret_cast<const bf16x8*>(&Bs[(wc * 64 + ct * 16 + lo) * LDS_K + kc * 32 + hi * 8]);
#pragma unroll
            for (int rt = 0; rt < 4; ++rt)
#pragma unroll
                for (int ct = 0; ct < 4; ++ct)
                    acc[rt][ct] = __builtin_amdgcn_mfma_f32_16x16x32_bf16(af[rt], bf[ct], acc[rt][ct], 0, 0, 0);
        }
    }

    // epilogue: bn + prelu per column, scattered bf16 stores
    float sc[4], sh[4], al[4];
#pragma unroll
    for (int ct = 0; ct < 4; ++ct) {
        const int c = n0 + wc * 64 + ct * 16 + lo;
        const float g  = bn[c];
        const float be = bn[HD + c];
        const float mu = bn[2 * HD + c];
        const float va = bn[3 * HD + c];
        sc[ct] = g * rsqrtf(va + BN_EPS);
        sh[ct] = be + (bias[c] - mu) * sc[ct];
        al[ct] = alpha ? alpha[c] : 1.0f;
    }
#pragma unroll
    for (int rt = 0; rt < 4; ++rt) {
#pragma unroll
        for (int i = 0; i < 4; ++i) {
            const int r = m0 + wr * 64 + rt * 16 + hi * 4 + i;
            if (r >= M) continue;
#pragma unroll
            for (int ct = 0; ct < 4; ++ct) {
                float v = acc[rt][ct][i] * sc[ct] + sh[ct];
                v = (v >= 0.f) ? v : al[ct] * v;
                unsigned short u = f2bf(v);
                out[(size_t)r * ldo + n0 + wc * 64 + ct * 16 + lo] = *reinterpret_cast<bf16*>(&u);
            }
        }
    }
}

// ---------------------------------------------------------------------------
// CSR build: histogram of tgt, exclusive scan, fill edge list.
// ---------------------------------------------------------------------------
__global__ __launch_bounds__(256)
void hist_tgt(const int* __restrict__ edge, int* __restrict__ ecnt)
{
    const int e = blockIdx.x * blockDim.x + threadIdx.x;
    if (e >= NEDGE) return;
    atomicAdd(&ecnt[edge[2 * e]], 1);
}

__global__ __launch_bounds__(1024)
void scan_counts(const int* __restrict__ ecnt,
                 int* __restrict__ off, int* __restrict__ cursor)
{
    __shared__ int part[1024];
    const int t = threadIdx.x;
    const int CH = (NN + 1023) / 1024;
    const int base = t * CH;

    int s = 0;
    for (int i = 0; i < CH; ++i) {
        const int idx = base + i;
        if (idx < NN) s += ecnt[idx];
    }
    part[t] = s;
    __syncthreads();
    for (int d = 1; d < 1024; d <<= 1) {
        const int v = (t >= d) ? part[t - d] : 0;
        __syncthreads();
        part[t] += v;
        __syncthreads();
    }
    int running = (t == 0) ? 0 : part[t - 1];
    for (int i = 0; i < CH; ++i) {
        const int idx = base + i;
        if (idx < NN) {
            off[idx] = running;
            cursor[idx] = running;
            running += ecnt[idx];
        }
    }
    if (t == 1023) off[NN] = part[1023];
}

__global__ __launch_bounds__(256)
void fill_elist(const int* __restrict__ edge,
                int* __restrict__ cursor, int* __restrict__ elist)
{
    const int e = blockIdx.x * blockDim.x + threadIdx.x;
    if (e >= NEDGE) return;
    const int tgt = edge[2 * e + 0];
    const int src = edge[2 * e + 1];
    const int pos = atomicAdd(&cursor[tgt], 1);
    elist[pos] = src;
}

// ---------------------------------------------------------------------------
// Atomic-free gather: dst[n,:] = sum_{j in off[n]..off[n+1]} h[elist[j],:]
// ---------------------------------------------------------------------------
__global__ __launch_bounds__(256)
void gather_nodes(const bf16* __restrict__ h,
                  const int* __restrict__ off,
                  const int* __restrict__ elist,
                  bf16* __restrict__ dst)
{
    const int node = blockIdx.x * 4 + (threadIdx.x >> 6);
    if (node >= NN) return;
    const int lane = threadIdx.x & 63;
    const int j0 = off[node];
    const int j1 = off[node + 1];

    float4 acc = make_float4(0.f, 0.f, 0.f, 0.f);
    for (int j = j0; j < j1; ++j) {
        const int src = elist[j];
        const ushort4 u = *reinterpret_cast<const ushort4*>(h + (size_t)src * HD + lane * 4);
        acc.x += bf2f(u.x);
        acc.y += bf2f(u.y);
        acc.z += bf2f(u.z);
        acc.w += bf2f(u.w);
    }
    ushort4 o;
    o.x = f2bf(acc.x); o.y = f2bf(acc.y); o.z = f2bf(acc.z); o.w = f2bf(acc.w);
    *reinterpret_cast<ushort4*>(dst + (size_t)node * ACT_LD + lane * 4) = o;
}

// ---------------------------------------------------------------------------
// post1 (256->1 dense + bn) fused with graph segment-sum.
// ---------------------------------------------------------------------------
__global__ __launch_bounds__(256)
void post1_segsum(const bf16* __restrict__ h,
                  const float* __restrict__ W,
                  const float* __restrict__ b,
                  const float* __restrict__ bn,
                  const int* __restrict__ seg,
                  float* __restrict__ outg)
{
    const int row = blockIdx.x * 4 + (threadIdx.x >> 6);
    const int lane = threadIdx.x & 63;
    float s = 0.f;
    if (row < NN) {
        const ushort4 u = *reinterpret_cast<const ushort4*>(h + (size_t)row * HD + lane * 4);
        const float4 wv = *reinterpret_cast<const float4*>(W + lane * 4);
        s = bf2f(u.x) * wv.x + bf2f(u.y) * wv.y + bf2f(u.z) * wv.z + bf2f(u.w) * wv.w;
    }
#pragma unroll
    for (int off = 32; off > 0; off >>= 1) s += __shfl_down(s, off);
    if (lane == 0 && row < NN) {
        const float g = bn[0], be = bn[1], mu = bn[2], va = bn[3];
        const float y = g * (s + b[0] - mu) * rsqrtf(va + BN_EPS) + be;
        atomicAdd(&outg[seg[row]], y);
    }
}

// ---------------------------------------------------------------------------
extern "C" void kernel_launch(void* const* d_in, const int* in_sizes, int n_in,
                              void* d_out, int out_size, void* d_ws, size_t ws_size,
                              hipStream_t stream)
{
    const float* x    = (const float*)d_in[0];
    const int*   edge = (const int*)d_in[1];
    const int*   seg  = (const int*)d_in[2];

    const float* Wsrc[7], *bi[7], *bnp[7], *ap[7];
    for (int L = 0; L < 7; ++L) {
        Wsrc[L] = (const float*)d_in[4 + 4 * L + 0];
        bi[L]   = (const float*)d_in[4 + 4 * L + 1];
        bnp[L]  = (const float*)d_in[4 + 4 * L + 2];
        ap[L]   = (const float*)d_in[4 + 4 * L + 3];
    }
    const float* post1_W  = (const float*)d_in[32];
    const float* post1_b  = (const float*)d_in[33];
    const float* post1_bn = (const float*)d_in[34];

    static const int Ks[7] = {128, 256, 256, 512, 768, 1024, 1280};

    // Workspace (~172 MB, fits the >=204.8 MB proven in round 2):
    bf16* act  = (bf16*)d_ws;                          // 128.0 MB
    bf16* h    = act + (size_t)NN * ACT_LD;            //  25.6 MB
    bf16* xb   = h + (size_t)NN * HD;                  //  12.8 MB
    bf16* wt0  = xb + (size_t)NN * 128;                //   2.16 MB total Wt
    bf16* WtB[7];
    {
        size_t o = 0;
        for (int L = 0; L < 7; ++L) { WtB[L] = wt0 + o; o += (size_t)Ks[L] * HD; }
    }
    int* ecnt   = (int*)(wt0 + (size_t)4224 * HD);
    int* off    = ecnt + NN;
    int* cursor = off + NN + 1;
    int* elist  = cursor + NN;

    hipMemsetAsync(d_out, 0, (size_t)out_size * sizeof(float), stream);
    hipMemsetAsync(ecnt, 0, NN * sizeof(int), stream);

    const dim3 blk(256);
    const dim3 gemm_grid((NN + BM - 1) / BM, HD / BN);   // (391, 2)
    const int  edge_grid = (NEDGE + 255) / 256;
    const int  node_grid = (NN + 3) / 4;

    // weight transposes (fp32 KxH -> bf16 HxK) + x conversion
    for (int L = 0; L < 7; ++L)
        transpose_w<<<dim3(Ks[L] / 32, HD / 32), blk, 0, stream>>>(Wsrc[L], WtB[L], Ks[L]);
    convert_x<<<(NN * 32 + 255) / 256, blk, 0, stream>>>(x, xb);

    // CSR build (reused by all 4 gconv layers)
    hist_tgt<<<edge_grid, blk, 0, stream>>>(edge, ecnt);
    scan_counts<<<1, 1024, 0, stream>>>(ecnt, off, cursor);
    fill_elist<<<edge_grid, blk, 0, stream>>>(edge, cursor, elist);

    // pre0: xb(K=128) -> h
    gemm_bn_act<<<gemm_grid, blk, 0, stream>>>(xb, 128, WtB[0], 128, bi[0], bnp[0], ap[0], h, HD, NN);
    // pre1: h(K=256) -> act[:,1024:1280) (= out1)
    gemm_bn_act<<<gemm_grid, blk, 0, stream>>>(h, HD, WtB[1], 256, bi[1], bnp[1], ap[1], act + 1024, ACT_LD, NN);

    // gconv layers: input = act cols [1024-256L, 1280), K = 256*(L+1)
    for (int L = 0; L < 4; ++L) {
        const int in_off = 1024 - 256 * L;
        const int K      = 256 * (L + 1);
        gemm_bn_act<<<gemm_grid, blk, 0, stream>>>(act + in_off, ACT_LD, WtB[2 + L], K, bi[2 + L], bnp[2 + L], ap[2 + L], h, HD, NN);
        gather_nodes<<<node_grid, blk, 0, stream>>>(h, off, elist, act + (in_off - 256));
    }

    // post0: act(K=1280) -> h
    gemm_bn_act<<<gemm_grid, blk, 0, stream>>>(act, ACT_LD, WtB[6], 1280, bi[6], bnp[6], ap[6], h, HD, NN);
    // post1 + segment-sum -> d_out (64 floats)
    post1_segsum<<<node_grid, blk, 0, stream>>>(h, post1_W, post1_b, post1_bn, seg, (float*)d_out);
}

// Round 5
// 925.436 us; speedup vs baseline: 14.5444x; 1.4078x over previous
//
#include <hip/hip_runtime.h>
#include <hip/hip_bf16.h>

#define NN 50000
#define NEDGE 800000
#define HD 256
#define ACT_LD 1280
#define NGRAPH 64
#define BN_EPS 1e-3f

#define BM 128
#define BN 128
#define BK 64
#define LDS_K 72   // shorts per LDS row: 64 data + 8 pad (144 B) -> full bank spread

using bf16 = __hip_bfloat16;
typedef __attribute__((ext_vector_type(8))) short bf16x8;  // 8 bf16 = 4 VGPR (MFMA A/B frag)
typedef __attribute__((ext_vector_type(4))) float f32x4;   // MFMA C/D frag

static __device__ __forceinline__ float bf2f(unsigned short u) {
    union { float f; unsigned int i; } c;
    c.i = ((unsigned int)u) << 16;
    return c.f;
}
static __device__ __forceinline__ unsigned short f2bf(float f) {
    bf16 t = __float2bfloat16(f);   // round-to-nearest-even
    return *reinterpret_cast<unsigned short*>(&t);
}

// ---------------------------------------------------------------------------
// W (K x 256 fp32, row-major) -> Wt (256 x K bf16, row-major)  [32x32 LDS tiles]
// ---------------------------------------------------------------------------
__global__ __launch_bounds__(256)
void transpose_w(const float* __restrict__ W, bf16* __restrict__ Wt, int K)
{
    __shared__ unsigned short T[32][33];
    const int k0 = blockIdx.x * 32;
    const int n0 = blockIdx.y * 32;
#pragma unroll
    for (int i = 0; i < 4; ++i) {
        const int idx = threadIdx.x + i * 256;
        const int kk = idx >> 5, nn = idx & 31;
        T[kk][nn] = f2bf(W[(size_t)(k0 + kk) * HD + n0 + nn]);
    }
    __syncthreads();
#pragma unroll
    for (int i = 0; i < 4; ++i) {
        const int idx = threadIdx.x + i * 256;
        const int nn = idx >> 5, kk = idx & 31;
        unsigned short v = T[kk][nn];
        Wt[(size_t)(n0 + nn) * K + k0 + kk] = *reinterpret_cast<bf16*>(&v);
    }
}

// ---------------------------------------------------------------------------
// x (N x 128 fp32) -> xb (N x 128 bf16)
// ---------------------------------------------------------------------------
__global__ __launch_bounds__(256)
void convert_x(const float* __restrict__ x, bf16* __restrict__ xb)
{
    const int i = blockIdx.x * blockDim.x + threadIdx.x;   // over NN*32 float4s
    if (i >= NN * 32) return;
    const float4 v = *reinterpret_cast<const float4*>(x + (size_t)i * 4);
    ushort4 o;
    o.x = f2bf(v.x); o.y = f2bf(v.y); o.z = f2bf(v.z); o.w = f2bf(v.w);
    *reinterpret_cast<ushort4*>((unsigned short*)xb + (size_t)i * 4) = o;
}

// ---------------------------------------------------------------------------
// MFMA GEMM + BN + PReLU:  out = prelu(bn(A @ W + b))
// A: M x K bf16 (lda), Wt: 256 x K bf16 (W transposed), out: bf16 (ldo).
// 128x128 tile, 4 waves (2x2), each wave 64x64 = 4x4 frags of 16x16x32.
// ---------------------------------------------------------------------------
__global__ __launch_bounds__(256)
void gemm_bn_act(const bf16* __restrict__ A, int lda,
                 const bf16* __restrict__ Wt, int K,
                 const float* __restrict__ bias,
                 const float* __restrict__ bn,
                 const float* __restrict__ alpha,
                 bf16* __restrict__ out, int ldo, int M)
{
    __shared__ short As[BM * LDS_K];
    __shared__ short Bs[BN * LDS_K];

    const int tid  = threadIdx.x;
    const int wid  = tid >> 6;
    const int lane = tid & 63;
    const int lo   = lane & 15;
    const int hi   = lane >> 4;
    const int wr   = wid >> 1;    // wave row 0..1
    const int wc   = wid & 1;     // wave col 0..1

    const int m0 = blockIdx.x * BM;
    const int n0 = blockIdx.y * BN;

    f32x4 acc[4][4] = {};   // [row-tile][col-tile]

    for (int k0 = 0; k0 < K; k0 += BK) {
        __syncthreads();
#pragma unroll
        for (int i = 0; i < 4; ++i) {
            const int ch  = tid + i * 256;     // 0..1023 : 16B chunks of the 128x64 tile
            const int row = ch >> 3;           // 0..127
            const int kc  = ch & 7;            // 8 x 16B per row
            uint4 av = make_uint4(0u, 0u, 0u, 0u);
            if (m0 + row < M)
                av = *reinterpret_cast<const uint4*>(A + (size_t)(m0 + row) * lda + k0 + kc * 8);
            *reinterpret_cast<uint4*>(&As[row * LDS_K + kc * 8]) = av;
            const uint4 bv = *reinterpret_cast<const uint4*>(Wt + (size_t)(n0 + row) * K + k0 + kc * 8);
            *reinterpret_cast<uint4*>(&Bs[row * LDS_K + kc * 8]) = bv;
        }
        __syncthreads();

#pragma unroll
        for (int kc = 0; kc < 2; ++kc) {       // two K=32 chunks
            bf16x8 af[4], bf[4];
#pragma unroll
            for (int rt = 0; rt < 4; ++rt)
                af[rt] = *reinterpret_cast<const bf16x8*>(&As[(wr * 64 + rt * 16 + lo) * LDS_K + kc * 32 + hi * 8]);
#pragma unroll
            for (int ct = 0; ct < 4; ++ct)
                bf[ct] = *reinterpret_cast<const bf16x8*>(&Bs[(wc * 64 + ct * 16 + lo) * LDS_K + kc * 32 + hi * 8]);
#pragma unroll
            for (int rt = 0; rt < 4; ++rt)
#pragma unroll
                for (int ct = 0; ct < 4; ++ct)
                    acc[rt][ct] = __builtin_amdgcn_mfma_f32_16x16x32_bf16(af[rt], bf[ct], acc[rt][ct], 0, 0, 0);
        }
    }

    // epilogue: bn + prelu per column, scattered bf16 stores
    float sc[4], sh[4], al[4];
#pragma unroll
    for (int ct = 0; ct < 4; ++ct) {
        const int c = n0 + wc * 64 + ct * 16 + lo;
        const float g  = bn[c];
        const float be = bn[HD + c];
        const float mu = bn[2 * HD + c];
        const float va = bn[3 * HD + c];
        sc[ct] = g * rsqrtf(va + BN_EPS);
        sh[ct] = be + (bias[c] - mu) * sc[ct];
        al[ct] = alpha ? alpha[c] : 1.0f;
    }
#pragma unroll
    for (int rt = 0; rt < 4; ++rt) {
#pragma unroll
        for (int i = 0; i < 4; ++i) {
            const int r = m0 + wr * 64 + rt * 16 + hi * 4 + i;
            if (r >= M) continue;
#pragma unroll
            for (int ct = 0; ct < 4; ++ct) {
                float v = acc[rt][ct][i] * sc[ct] + sh[ct];
                v = (v >= 0.f) ? v : al[ct] * v;
                unsigned short u = f2bf(v);
                out[(size_t)r * ldo + n0 + wc * 64 + ct * 16 + lo] = *reinterpret_cast<bf16*>(&u);
            }
        }
    }
}

// ---------------------------------------------------------------------------
// CSR build: histogram of tgt, exclusive scan, fill edge list.
// ---------------------------------------------------------------------------
__global__ __launch_bounds__(256)
void hist_tgt(const int* __restrict__ edge, int* __restrict__ ecnt)
{
    const int e = blockIdx.x * blockDim.x + threadIdx.x;
    if (e >= NEDGE) return;
    atomicAdd(&ecnt[edge[2 * e]], 1);
}

__global__ __launch_bounds__(1024)
void scan_counts(const int* __restrict__ ecnt,
                 int* __restrict__ off, int* __restrict__ cursor)
{
    __shared__ int part[1024];
    const int t = threadIdx.x;
    const int CH = (NN + 1023) / 1024;
    const int base = t * CH;

    int s = 0;
    for (int i = 0; i < CH; ++i) {
        const int idx = base + i;
        if (idx < NN) s += ecnt[idx];
    }
    part[t] = s;
    __syncthreads();
    for (int d = 1; d < 1024; d <<= 1) {
        const int v = (t >= d) ? part[t - d] : 0;
        __syncthreads();
        part[t] += v;
        __syncthreads();
    }
    int running = (t == 0) ? 0 : part[t - 1];
    for (int i = 0; i < CH; ++i) {
        const int idx = base + i;
        if (idx < NN) {
            off[idx] = running;
            cursor[idx] = running;
            running += ecnt[idx];
        }
    }
    if (t == 1023) off[NN] = part[1023];
}

__global__ __launch_bounds__(256)
void fill_elist(const int* __restrict__ edge,
                int* __restrict__ cursor, int* __restrict__ elist)
{
    const int e = blockIdx.x * blockDim.x + threadIdx.x;
    if (e >= NEDGE) return;
    const int tgt = edge[2 * e + 0];
    const int src = edge[2 * e + 1];
    const int pos = atomicAdd(&cursor[tgt], 1);
    elist[pos] = src;
}

// ---------------------------------------------------------------------------
// Atomic-free gather: dst[n,:] = sum_{j in off[n]..off[n+1]} h[elist[j],:]
// ---------------------------------------------------------------------------
__global__ __launch_bounds__(256)
void gather_nodes(const bf16* __restrict__ h,
                  const int* __restrict__ off,
                  const int* __restrict__ elist,
                  bf16* __restrict__ dst)
{
    const int node = blockIdx.x * 4 + (threadIdx.x >> 6);
    if (node >= NN) return;
    const int lane = threadIdx.x & 63;
    const int j0 = off[node];
    const int j1 = off[node + 1];

    float4 acc = make_float4(0.f, 0.f, 0.f, 0.f);
    for (int j = j0; j < j1; ++j) {
        const int src = elist[j];
        const ushort4 u = *reinterpret_cast<const ushort4*>(h + (size_t)src * HD + lane * 4);
        acc.x += bf2f(u.x);
        acc.y += bf2f(u.y);
        acc.z += bf2f(u.z);
        acc.w += bf2f(u.w);
    }
    ushort4 o;
    o.x = f2bf(acc.x); o.y = f2bf(acc.y); o.z = f2bf(acc.z); o.w = f2bf(acc.w);
    *reinterpret_cast<ushort4*>(dst + (size_t)node * ACT_LD + lane * 4) = o;
}

// ---------------------------------------------------------------------------
// post1 (256->1 dense + bn) fused with graph segment-sum.
// Hierarchical: per-row wave dot -> LDS graph bins -> one global atomic per
// NON-ZERO bin per block (seg sorted => ~1-2 distinct graphs per 64 rows).
// ---------------------------------------------------------------------------
__global__ __launch_bounds__(256)
void post1_segsum(const bf16* __restrict__ h,
                  const float* __restrict__ W,
                  const float* __restrict__ b,
                  const float* __restrict__ bn,
                  const int* __restrict__ seg,
                  float* __restrict__ outg)
{
    __shared__ float bins[NGRAPH];
    const int t = threadIdx.x;
    if (t < NGRAPH) bins[t] = 0.f;
    __syncthreads();

    const int wave = t >> 6;
    const int lane = t & 63;
    const float4 wv = *reinterpret_cast<const float4*>(W + lane * 4);
    const float g = bn[0], be = bn[1], mu = bn[2], va = bn[3];
    const float bscale = g * rsqrtf(va + BN_EPS);
    const float b0 = b[0];

    const int row0 = blockIdx.x * 64 + wave * 16;
#pragma unroll
    for (int i = 0; i < 16; ++i) {
        const int row = row0 + i;
        if (row >= NN) break;
        const ushort4 u = *reinterpret_cast<const ushort4*>(h + (size_t)row * HD + lane * 4);
        float s = bf2f(u.x) * wv.x + bf2f(u.y) * wv.y + bf2f(u.z) * wv.z + bf2f(u.w) * wv.w;
#pragma unroll
        for (int off = 32; off > 0; off >>= 1) s += __shfl_down(s, off);
        if (lane == 0) {
            const float y = bscale * (s + b0 - mu) + be;
            atomicAdd(&bins[seg[row]], y);
        }
    }
    __syncthreads();
    if (t < NGRAPH && bins[t] != 0.f) atomicAdd(&outg[t], bins[t]);
}

// ---------------------------------------------------------------------------
extern "C" void kernel_launch(void* const* d_in, const int* in_sizes, int n_in,
                              void* d_out, int out_size, void* d_ws, size_t ws_size,
                              hipStream_t stream)
{
    const float* x    = (const float*)d_in[0];
    const int*   edge = (const int*)d_in[1];
    const int*   seg  = (const int*)d_in[2];

    const float* Wsrc[7], *bi[7], *bnp[7], *ap[7];
    for (int L = 0; L < 7; ++L) {
        Wsrc[L] = (const float*)d_in[4 + 4 * L + 0];
        bi[L]   = (const float*)d_in[4 + 4 * L + 1];
        bnp[L]  = (const float*)d_in[4 + 4 * L + 2];
        ap[L]   = (const float*)d_in[4 + 4 * L + 3];
    }
    const float* post1_W  = (const float*)d_in[32];
    const float* post1_b  = (const float*)d_in[33];
    const float* post1_bn = (const float*)d_in[34];

    static const int Ks[7] = {128, 256, 256, 512, 768, 1024, 1280};

    // Workspace (~172 MB):
    bf16* act  = (bf16*)d_ws;                          // 128.0 MB
    bf16* h    = act + (size_t)NN * ACT_LD;            //  25.6 MB
    bf16* xb   = h + (size_t)NN * HD;                  //  12.8 MB
    bf16* wt0  = xb + (size_t)NN * 128;                //   2.16 MB total Wt
    bf16* WtB[7];
    {
        size_t o = 0;
        for (int L = 0; L < 7; ++L) { WtB[L] = wt0 + o; o += (size_t)Ks[L] * HD; }
    }
    int* ecnt   = (int*)(wt0 + (size_t)4224 * HD);
    int* off    = ecnt + NN;
    int* cursor = off + NN + 1;
    int* elist  = cursor + NN;

    hipMemsetAsync(d_out, 0, (size_t)out_size * sizeof(float), stream);
    hipMemsetAsync(ecnt, 0, NN * sizeof(int), stream);

    const dim3 blk(256);
    const dim3 gemm_grid((NN + BM - 1) / BM, HD / BN);   // (391, 2)
    const int  edge_grid = (NEDGE + 255) / 256;
    const int  node_grid = (NN + 3) / 4;

    // weight transposes (fp32 KxH -> bf16 HxK) + x conversion
    for (int L = 0; L < 7; ++L)
        transpose_w<<<dim3(Ks[L] / 32, HD / 32), blk, 0, stream>>>(Wsrc[L], WtB[L], Ks[L]);
    convert_x<<<(NN * 32 + 255) / 256, blk, 0, stream>>>(x, xb);

    // CSR build (reused by all 4 gconv layers)
    hist_tgt<<<edge_grid, blk, 0, stream>>>(edge, ecnt);
    scan_counts<<<1, 1024, 0, stream>>>(ecnt, off, cursor);
    fill_elist<<<edge_grid, blk, 0, stream>>>(edge, cursor, elist);

    // pre0: xb(K=128) -> h
    gemm_bn_act<<<gemm_grid, blk, 0, stream>>>(xb, 128, WtB[0], 128, bi[0], bnp[0], ap[0], h, HD, NN);
    // pre1: h(K=256) -> act[:,1024:1280) (= out1)
    gemm_bn_act<<<gemm_grid, blk, 0, stream>>>(h, HD, WtB[1], 256, bi[1], bnp[1], ap[1], act + 1024, ACT_LD, NN);

    // gconv layers: input = act cols [1024-256L, 1280), K = 256*(L+1)
    for (int L = 0; L < 4; ++L) {
        const int in_off = 1024 - 256 * L;
        const int K      = 256 * (L + 1);
        gemm_bn_act<<<gemm_grid, blk, 0, stream>>>(act + in_off, ACT_LD, WtB[2 + L], K, bi[2 + L], bnp[2 + L], ap[2 + L], h, HD, NN);
        gather_nodes<<<node_grid, blk, 0, stream>>>(h, off, elist, act + (in_off - 256));
    }

    // post0: act(K=1280) -> h
    gemm_bn_act<<<gemm_grid, blk, 0, stream>>>(act, ACT_LD, WtB[6], 1280, bi[6], bnp[6], ap[6], h, HD, NN);
    // post1 + segment-sum -> d_out (64 floats)
    post1_segsum<<<(NN + 63) / 64, blk, 0, stream>>>(h, post1_W, post1_b, post1_bn, seg, (float*)d_out);
}

// Round 6
// 813.433 us; speedup vs baseline: 16.5470x; 1.1377x over previous
//
#include <hip/hip_runtime.h>
#include <hip/hip_bf16.h>

#define NN 50000
#define NEDGE 800000
#define HD 256
#define ACT_LD 1280
#define NGRAPH 64
#define BN_EPS 1e-3f

#define BM 128
#define BN 128
#define BK 64
#define LDS_K 72   // shorts per LDS row: 64 data + 8 pad (144 B) -> full bank spread

#define SCAN_NBLK ((NN + 255) / 256)   // 196

using bf16 = __hip_bfloat16;
typedef __attribute__((ext_vector_type(8))) short bf16x8;  // 8 bf16 = 4 VGPR (MFMA A/B frag)
typedef __attribute__((ext_vector_type(4))) float f32x4;   // MFMA C/D frag

static __device__ __forceinline__ float bf2f(unsigned short u) {
    union { float f; unsigned int i; } c;
    c.i = ((unsigned int)u) << 16;
    return c.f;
}
static __device__ __forceinline__ unsigned short f2bf(float f) {
    bf16 t = __float2bfloat16(f);   // round-to-nearest-even
    return *reinterpret_cast<unsigned short*>(&t);
}

// ---------------------------------------------------------------------------
// W (K x 256 fp32, row-major) -> Wt (256 x K bf16, row-major)  [32x32 LDS tiles]
// ---------------------------------------------------------------------------
__global__ __launch_bounds__(256)
void transpose_w(const float* __restrict__ W, bf16* __restrict__ Wt, int K)
{
    __shared__ unsigned short T[32][33];
    const int k0 = blockIdx.x * 32;
    const int n0 = blockIdx.y * 32;
#pragma unroll
    for (int i = 0; i < 4; ++i) {
        const int idx = threadIdx.x + i * 256;
        const int kk = idx >> 5, nn = idx & 31;
        T[kk][nn] = f2bf(W[(size_t)(k0 + kk) * HD + n0 + nn]);
    }
    __syncthreads();
#pragma unroll
    for (int i = 0; i < 4; ++i) {
        const int idx = threadIdx.x + i * 256;
        const int nn = idx >> 5, kk = idx & 31;
        unsigned short v = T[kk][nn];
        Wt[(size_t)(n0 + nn) * K + k0 + kk] = *reinterpret_cast<bf16*>(&v);
    }
}

// ---------------------------------------------------------------------------
// x (N x 128 fp32) -> xb (N x 128 bf16)
// ---------------------------------------------------------------------------
__global__ __launch_bounds__(256)
void convert_x(const float* __restrict__ x, bf16* __restrict__ xb)
{
    const int i = blockIdx.x * blockDim.x + threadIdx.x;   // over NN*32 float4s
    if (i >= NN * 32) return;
    const float4 v = *reinterpret_cast<const float4*>(x + (size_t)i * 4);
    ushort4 o;
    o.x = f2bf(v.x); o.y = f2bf(v.y); o.z = f2bf(v.z); o.w = f2bf(v.w);
    *reinterpret_cast<ushort4*>((unsigned short*)xb + (size_t)i * 4) = o;
}

// ---------------------------------------------------------------------------
// MFMA GEMM + BN + PReLU:  out = prelu(bn(A @ W + b))
// ---------------------------------------------------------------------------
__global__ __launch_bounds__(256)
void gemm_bn_act(const bf16* __restrict__ A, int lda,
                 const bf16* __restrict__ Wt, int K,
                 const float* __restrict__ bias,
                 const float* __restrict__ bn,
                 const float* __restrict__ alpha,
                 bf16* __restrict__ out, int ldo, int M)
{
    __shared__ short As[BM * LDS_K];
    __shared__ short Bs[BN * LDS_K];

    const int tid  = threadIdx.x;
    const int wid  = tid >> 6;
    const int lane = tid & 63;
    const int lo   = lane & 15;
    const int hi   = lane >> 4;
    const int wr   = wid >> 1;    // wave row 0..1
    const int wc   = wid & 1;     // wave col 0..1

    const int m0 = blockIdx.x * BM;
    const int n0 = blockIdx.y * BN;

    f32x4 acc[4][4] = {};   // [row-tile][col-tile]

    for (int k0 = 0; k0 < K; k0 += BK) {
        __syncthreads();
#pragma unroll
        for (int i = 0; i < 4; ++i) {
            const int ch  = tid + i * 256;     // 0..1023 : 16B chunks of the 128x64 tile
            const int row = ch >> 3;           // 0..127
            const int kc  = ch & 7;            // 8 x 16B per row
            uint4 av = make_uint4(0u, 0u, 0u, 0u);
            if (m0 + row < M)
                av = *reinterpret_cast<const uint4*>(A + (size_t)(m0 + row) * lda + k0 + kc * 8);
            *reinterpret_cast<uint4*>(&As[row * LDS_K + kc * 8]) = av;
            const uint4 bv = *reinterpret_cast<const uint4*>(Wt + (size_t)(n0 + row) * K + k0 + kc * 8);
            *reinterpret_cast<uint4*>(&Bs[row * LDS_K + kc * 8]) = bv;
        }
        __syncthreads();

#pragma unroll
        for (int kc = 0; kc < 2; ++kc) {       // two K=32 chunks
            bf16x8 af[4], bf[4];
#pragma unroll
            for (int rt = 0; rt < 4; ++rt)
                af[rt] = *reinterpret_cast<const bf16x8*>(&As[(wr * 64 + rt * 16 + lo) * LDS_K + kc * 32 + hi * 8]);
#pragma unroll
            for (int ct = 0; ct < 4; ++ct)
                bf[ct] = *reinterpret_cast<const bf16x8*>(&Bs[(wc * 64 + ct * 16 + lo) * LDS_K + kc * 32 + hi * 8]);
#pragma unroll
            for (int rt = 0; rt < 4; ++rt)
#pragma unroll
                for (int ct = 0; ct < 4; ++ct)
                    acc[rt][ct] = __builtin_amdgcn_mfma_f32_16x16x32_bf16(af[rt], bf[ct], acc[rt][ct], 0, 0, 0);
        }
    }

    // epilogue: bn + prelu per column, scattered bf16 stores
    float sc[4], sh[4], al[4];
#pragma unroll
    for (int ct = 0; ct < 4; ++ct) {
        const int c = n0 + wc * 64 + ct * 16 + lo;
        const float g  = bn[c];
        const float be = bn[HD + c];
        const float mu = bn[2 * HD + c];
        const float va = bn[3 * HD + c];
        sc[ct] = g * rsqrtf(va + BN_EPS);
        sh[ct] = be + (bias[c] - mu) * sc[ct];
        al[ct] = alpha ? alpha[c] : 1.0f;
    }
#pragma unroll
    for (int rt = 0; rt < 4; ++rt) {
#pragma unroll
        for (int i = 0; i < 4; ++i) {
            const int r = m0 + wr * 64 + rt * 16 + hi * 4 + i;
            if (r >= M) continue;
#pragma unroll
            for (int ct = 0; ct < 4; ++ct) {
                float v = acc[rt][ct][i] * sc[ct] + sh[ct];
                v = (v >= 0.f) ? v : al[ct] * v;
                unsigned short u = f2bf(v);
                out[(size_t)r * ldo + n0 + wc * 64 + ct * 16 + lo] = *reinterpret_cast<bf16*>(&u);
            }
        }
    }
}

// ---------------------------------------------------------------------------
// CSR build: histogram, 3-stage parallel scan, fill edge list.
// ---------------------------------------------------------------------------
__global__ __launch_bounds__(256)
void hist_tgt(const int* __restrict__ edge, int* __restrict__ ecnt)
{
    const int e = blockIdx.x * blockDim.x + threadIdx.x;
    if (e >= NEDGE) return;
    atomicAdd(&ecnt[edge[2 * e]], 1);
}

__global__ __launch_bounds__(256)
void block_sums(const int* __restrict__ ecnt, int* __restrict__ bsum)
{
    __shared__ int red[256];
    const int t = threadIdx.x;
    const int idx = blockIdx.x * 256 + t;
    red[t] = (idx < NN) ? ecnt[idx] : 0;
    __syncthreads();
#pragma unroll
    for (int d = 128; d > 0; d >>= 1) {
        if (t < d) red[t] += red[t + d];
        __syncthreads();
    }
    if (t == 0) bsum[blockIdx.x] = red[0];
}

__global__ __launch_bounds__(256)
void scan_bsums(const int* __restrict__ bsum, int* __restrict__ bbase,
                int* __restrict__ off)
{
    __shared__ int s[256];
    const int t = threadIdx.x;
    s[t] = (t < SCAN_NBLK) ? bsum[t] : 0;
    __syncthreads();
    for (int d = 1; d < 256; d <<= 1) {
        const int v = (t >= d) ? s[t - d] : 0;
        __syncthreads();
        s[t] += v;
        __syncthreads();
    }
    if (t < SCAN_NBLK) bbase[t] = (t == 0) ? 0 : s[t - 1];
    if (t == 255) off[NN] = s[255];   // total = NEDGE
}

__global__ __launch_bounds__(256)
void block_scan(const int* __restrict__ ecnt, const int* __restrict__ bbase,
                int* __restrict__ off, int* __restrict__ cursor)
{
    __shared__ int s[256];
    const int t = threadIdx.x;
    const int idx = blockIdx.x * 256 + t;
    const int v = (idx < NN) ? ecnt[idx] : 0;
    s[t] = v;
    __syncthreads();
    for (int d = 1; d < 256; d <<= 1) {
        const int x = (t >= d) ? s[t - d] : 0;
        __syncthreads();
        s[t] += x;
        __syncthreads();
    }
    if (idx < NN) {
        const int excl = bbase[blockIdx.x] + s[t] - v;   // exclusive prefix
        off[idx] = excl;
        cursor[idx] = excl;
    }
}

__global__ __launch_bounds__(256)
void fill_elist(const int* __restrict__ edge,
                int* __restrict__ cursor, int* __restrict__ elist)
{
    const int e = blockIdx.x * blockDim.x + threadIdx.x;
    if (e >= NEDGE) return;
    const int tgt = edge[2 * e + 0];
    const int src = edge[2 * e + 1];
    const int pos = atomicAdd(&cursor[tgt], 1);
    elist[pos] = src;
}

// ---------------------------------------------------------------------------
// Atomic-free gather: dst[n,:] = sum_{j in off[n]..off[n+1]} h[elist[j],:]
// ---------------------------------------------------------------------------
__global__ __launch_bounds__(256)
void gather_nodes(const bf16* __restrict__ h,
                  const int* __restrict__ off,
                  const int* __restrict__ elist,
                  bf16* __restrict__ dst)
{
    const int node = blockIdx.x * 4 + (threadIdx.x >> 6);
    if (node >= NN) return;
    const int lane = threadIdx.x & 63;
    const int j0 = off[node];
    const int j1 = off[node + 1];

    float4 acc = make_float4(0.f, 0.f, 0.f, 0.f);
    for (int j = j0; j < j1; ++j) {
        const int src = elist[j];
        const ushort4 u = *reinterpret_cast<const ushort4*>(h + (size_t)src * HD + lane * 4);
        acc.x += bf2f(u.x);
        acc.y += bf2f(u.y);
        acc.z += bf2f(u.z);
        acc.w += bf2f(u.w);
    }
    ushort4 o;
    o.x = f2bf(acc.x); o.y = f2bf(acc.y); o.z = f2bf(acc.z); o.w = f2bf(acc.w);
    *reinterpret_cast<ushort4*>(dst + (size_t)node * ACT_LD + lane * 4) = o;
}

// ---------------------------------------------------------------------------
// post1 (256->1 dense + bn) fused with graph segment-sum (hierarchical).
// ---------------------------------------------------------------------------
__global__ __launch_bounds__(256)
void post1_segsum(const bf16* __restrict__ h,
                  const float* __restrict__ W,
                  const float* __restrict__ b,
                  const float* __restrict__ bn,
                  const int* __restrict__ seg,
                  float* __restrict__ outg)
{
    __shared__ float bins[NGRAPH];
    const int t = threadIdx.x;
    if (t < NGRAPH) bins[t] = 0.f;
    __syncthreads();

    const int wave = t >> 6;
    const int lane = t & 63;
    const float4 wv = *reinterpret_cast<const float4*>(W + lane * 4);
    const float g = bn[0], be = bn[1], mu = bn[2], va = bn[3];
    const float bscale = g * rsqrtf(va + BN_EPS);
    const float b0 = b[0];

    const int row0 = blockIdx.x * 64 + wave * 16;
#pragma unroll
    for (int i = 0; i < 16; ++i) {
        const int row = row0 + i;
        if (row >= NN) break;
        const ushort4 u = *reinterpret_cast<const ushort4*>(h + (size_t)row * HD + lane * 4);
        float s = bf2f(u.x) * wv.x + bf2f(u.y) * wv.y + bf2f(u.z) * wv.z + bf2f(u.w) * wv.w;
#pragma unroll
        for (int off = 32; off > 0; off >>= 1) s += __shfl_down(s, off);
        if (lane == 0) {
            const float y = bscale * (s + b0 - mu) + be;
            atomicAdd(&bins[seg[row]], y);
        }
    }
    __syncthreads();
    if (t < NGRAPH && bins[t] != 0.f) atomicAdd(&outg[t], bins[t]);
}

// ---------------------------------------------------------------------------
extern "C" void kernel_launch(void* const* d_in, const int* in_sizes, int n_in,
                              void* d_out, int out_size, void* d_ws, size_t ws_size,
                              hipStream_t stream)
{
    const float* x    = (const float*)d_in[0];
    const int*   edge = (const int*)d_in[1];
    const int*   seg  = (const int*)d_in[2];

    const float* Wsrc[7], *bi[7], *bnp[7], *ap[7];
    for (int L = 0; L < 7; ++L) {
        Wsrc[L] = (const float*)d_in[4 + 4 * L + 0];
        bi[L]   = (const float*)d_in[4 + 4 * L + 1];
        bnp[L]  = (const float*)d_in[4 + 4 * L + 2];
        ap[L]   = (const float*)d_in[4 + 4 * L + 3];
    }
    const float* post1_W  = (const float*)d_in[32];
    const float* post1_b  = (const float*)d_in[33];
    const float* post1_bn = (const float*)d_in[34];

    static const int Ks[7] = {128, 256, 256, 512, 768, 1024, 1280};

    // Workspace (~172 MB):
    bf16* act  = (bf16*)d_ws;                          // 128.0 MB
    bf16* h    = act + (size_t)NN * ACT_LD;            //  25.6 MB
    bf16* xb   = h + (size_t)NN * HD;                  //  12.8 MB
    bf16* wt0  = xb + (size_t)NN * 128;                //   2.16 MB total Wt
    bf16* WtB[7];
    {
        size_t o = 0;
        for (int L = 0; L < 7; ++L) { WtB[L] = wt0 + o; o += (size_t)Ks[L] * HD; }
    }
    int* ecnt   = (int*)(wt0 + (size_t)4224 * HD);
    int* off    = ecnt + NN;
    int* cursor = off + NN + 1;
    int* elist  = cursor + NN;
    int* bsum   = elist + NEDGE;
    int* bbase  = bsum + SCAN_NBLK;

    hipMemsetAsync(d_out, 0, (size_t)out_size * sizeof(float), stream);
    hipMemsetAsync(ecnt, 0, NN * sizeof(int), stream);

    const dim3 blk(256);
    const dim3 gemm_grid((NN + BM - 1) / BM, HD / BN);   // (391, 2)
    const int  edge_grid = (NEDGE + 255) / 256;
    const int  node_grid = (NN + 3) / 4;

    // weight transposes (fp32 KxH -> bf16 HxK) + x conversion
    for (int L = 0; L < 7; ++L)
        transpose_w<<<dim3(Ks[L] / 32, HD / 32), blk, 0, stream>>>(Wsrc[L], WtB[L], Ks[L]);
    convert_x<<<(NN * 32 + 255) / 256, blk, 0, stream>>>(x, xb);

    // CSR build (reused by all 4 gconv layers)
    hist_tgt<<<edge_grid, blk, 0, stream>>>(edge, ecnt);
    block_sums<<<SCAN_NBLK, blk, 0, stream>>>(ecnt, bsum);
    scan_bsums<<<1, blk, 0, stream>>>(bsum, bbase, off);
    block_scan<<<SCAN_NBLK, blk, 0, stream>>>(ecnt, bbase, off, cursor);
    fill_elist<<<edge_grid, blk, 0, stream>>>(edge, cursor, elist);

    // pre0: xb(K=128) -> h
    gemm_bn_act<<<gemm_grid, blk, 0, stream>>>(xb, 128, WtB[0], 128, bi[0], bnp[0], ap[0], h, HD, NN);
    // pre1: h(K=256) -> act[:,1024:1280) (= out1)
    gemm_bn_act<<<gemm_grid, blk, 0, stream>>>(h, HD, WtB[1], 256, bi[1], bnp[1], ap[1], act + 1024, ACT_LD, NN);

    // gconv layers: input = act cols [1024-256L, 1280), K = 256*(L+1)
    for (int L = 0; L < 4; ++L) {
        const int in_off = 1024 - 256 * L;
        const int K      = 256 * (L + 1);
        gemm_bn_act<<<gemm_grid, blk, 0, stream>>>(act + in_off, ACT_LD, WtB[2 + L], K, bi[2 + L], bnp[2 + L], ap[2 + L], h, HD, NN);
        gather_nodes<<<node_grid, blk, 0, stream>>>(h, off, elist, act + (in_off - 256));
    }

    // post0: act(K=1280) -> h
    gemm_bn_act<<<gemm_grid, blk, 0, stream>>>(act, ACT_LD, WtB[6], 1280, bi[6], bnp[6], ap[6], h, HD, NN);
    // post1 + segment-sum -> d_out (64 floats)
    post1_segsum<<<(NN + 63) / 64, blk, 0, stream>>>(h, post1_W, post1_b, post1_bn, seg, (float*)d_out);
}

// Round 7
// 744.848 us; speedup vs baseline: 18.0706x; 1.0921x over previous
//
#include <hip/hip_runtime.h>
#include <hip/hip_bf16.h>

#define NN 50000
#define NEDGE 800000
#define HD 256
#define ACT_LD 1280
#define NGRAPH 64
#define BN_EPS 1e-3f

#define BM 128
#define BN 128
#define BK 64          // shorts per LDS row (linear, NO padding: global_load_lds needs contiguous dest)

#define SCAN_NBLK ((NN + 255) / 256)   // 196

using bf16 = __hip_bfloat16;
typedef __attribute__((ext_vector_type(8))) short bf16x8;  // 8 bf16 = 4 VGPR (MFMA A/B frag)
typedef __attribute__((ext_vector_type(4))) float f32x4;   // MFMA C/D frag

#define GLB(p) ((const __attribute__((address_space(1))) void*)(p))
#define LDS(p) ((__attribute__((address_space(3))) void*)(p))

static __device__ __forceinline__ float bf2f(unsigned short u) {
    union { float f; unsigned int i; } c;
    c.i = ((unsigned int)u) << 16;
    return c.f;
}
static __device__ __forceinline__ unsigned short f2bf(float f) {
    bf16 t = __float2bfloat16(f);   // round-to-nearest-even
    return *reinterpret_cast<unsigned short*>(&t);
}

// ---------------------------------------------------------------------------
// W (K x 256 fp32, row-major) -> Wt (256 x K bf16, row-major)  [32x32 LDS tiles]
// ---------------------------------------------------------------------------
__global__ __launch_bounds__(256)
void transpose_w(const float* __restrict__ W, bf16* __restrict__ Wt, int K)
{
    __shared__ unsigned short T[32][33];
    const int k0 = blockIdx.x * 32;
    const int n0 = blockIdx.y * 32;
#pragma unroll
    for (int i = 0; i < 4; ++i) {
        const int idx = threadIdx.x + i * 256;
        const int kk = idx >> 5, nn = idx & 31;
        T[kk][nn] = f2bf(W[(size_t)(k0 + kk) * HD + n0 + nn]);
    }
    __syncthreads();
#pragma unroll
    for (int i = 0; i < 4; ++i) {
        const int idx = threadIdx.x + i * 256;
        const int nn = idx >> 5, kk = idx & 31;
        unsigned short v = T[kk][nn];
        Wt[(size_t)(n0 + nn) * K + k0 + kk] = *reinterpret_cast<bf16*>(&v);
    }
}

// ---------------------------------------------------------------------------
// x (N x 128 fp32) -> xb (N x 128 bf16)
// ---------------------------------------------------------------------------
__global__ __launch_bounds__(256)
void convert_x(const float* __restrict__ x, bf16* __restrict__ xb)
{
    const int i = blockIdx.x * blockDim.x + threadIdx.x;   // over NN*32 float4s
    if (i >= NN * 32) return;
    const float4 v = *reinterpret_cast<const float4*>(x + (size_t)i * 4);
    ushort4 o;
    o.x = f2bf(v.x); o.y = f2bf(v.y); o.z = f2bf(v.z); o.w = f2bf(v.w);
    *reinterpret_cast<ushort4*>((unsigned short*)xb + (size_t)i * 4) = o;
}

// ---------------------------------------------------------------------------
// MFMA GEMM + BN + PReLU:  out = prelu(bn(A @ W + b))
// A: M x K bf16 (lda), Wt: 256 x K bf16, out: bf16 (ldo).
// 128x128 tile, BK=64, 4 waves (2x2); staging via global_load_lds width=16
// into LINEAR LDS [128][64] (m97 structure).
// ---------------------------------------------------------------------------
__global__ __launch_bounds__(256)
void gemm_bn_act(const bf16* __restrict__ A, int lda,
                 const bf16* __restrict__ Wt, int K,
                 const float* __restrict__ bias,
                 const float* __restrict__ bn,
                 const float* __restrict__ alpha,
                 bf16* __restrict__ out, int ldo, int M)
{
    __shared__ short As[BM * BK];   // 16 KB, linear [row][64]
    __shared__ short Bs[BN * BK];   // 16 KB

    const int tid  = threadIdx.x;
    const int wid  = tid >> 6;
    const int lane = tid & 63;
    const int lo   = lane & 15;
    const int hi   = lane >> 4;
    const int wr   = wid >> 1;    // wave row 0..1
    const int wc   = wid & 1;     // wave col 0..1

    const int m0 = blockIdx.x * BM;
    const int n0 = blockIdx.y * BN;

    // per-lane staging geometry: each wave-issue covers 8 rows x 128 B
    const int srow = lane >> 3;        // 0..7 row within group
    const int sel  = (lane & 7) * 8;   // element offset within row (8 bf16 = 16 B)

    f32x4 acc[4][4] = {};   // [row-tile][col-tile]

    for (int k0 = 0; k0 < K; k0 += BK) {
        __syncthreads();   // previous iter's ds_reads done before overwrite
#pragma unroll
        for (int i = 0; i < 4; ++i) {
            const int grp = wid * 4 + i;              // 8-row group 0..15
            const int row = grp * 8 + srow;
            const int ar  = (m0 + row < M) ? (m0 + row) : (M - 1);   // clamp: dead rows never stored
            __builtin_amdgcn_global_load_lds(GLB(A + (size_t)ar * lda + k0 + sel),
                                             LDS(&As[grp * 8 * BK]), 16, 0, 0);
            __builtin_amdgcn_global_load_lds(GLB(Wt + (size_t)(n0 + row) * K + k0 + sel),
                                             LDS(&Bs[grp * 8 * BK]), 16, 0, 0);
        }
        __syncthreads();   // compiler drains vmcnt(0) before barrier -> LDS ready

#pragma unroll
        for (int kc = 0; kc < 2; ++kc) {       // two K=32 chunks
            bf16x8 af[4], bfr[4];
#pragma unroll
            for (int rt = 0; rt < 4; ++rt)
                af[rt] = *reinterpret_cast<const bf16x8*>(&As[(wr * 64 + rt * 16 + lo) * BK + kc * 32 + hi * 8]);
#pragma unroll
            for (int ct = 0; ct < 4; ++ct)
                bfr[ct] = *reinterpret_cast<const bf16x8*>(&Bs[(wc * 64 + ct * 16 + lo) * BK + kc * 32 + hi * 8]);
#pragma unroll
            for (int rt = 0; rt < 4; ++rt)
#pragma unroll
                for (int ct = 0; ct < 4; ++ct)
                    acc[rt][ct] = __builtin_amdgcn_mfma_f32_16x16x32_bf16(af[rt], bfr[ct], acc[rt][ct], 0, 0, 0);
        }
    }

    // epilogue: bn + prelu per column, scattered bf16 stores
    float sc[4], sh[4], al[4];
#pragma unroll
    for (int ct = 0; ct < 4; ++ct) {
        const int c = n0 + wc * 64 + ct * 16 + lo;
        const float g  = bn[c];
        const float be = bn[HD + c];
        const float mu = bn[2 * HD + c];
        const float va = bn[3 * HD + c];
        sc[ct] = g * rsqrtf(va + BN_EPS);
        sh[ct] = be + (bias[c] - mu) * sc[ct];
        al[ct] = alpha ? alpha[c] : 1.0f;
    }
#pragma unroll
    for (int rt = 0; rt < 4; ++rt) {
#pragma unroll
        for (int i = 0; i < 4; ++i) {
            const int r = m0 + wr * 64 + rt * 16 + hi * 4 + i;
            if (r >= M) continue;
#pragma unroll
            for (int ct = 0; ct < 4; ++ct) {
                float v = acc[rt][ct][i] * sc[ct] + sh[ct];
                v = (v >= 0.f) ? v : al[ct] * v;
                unsigned short u = f2bf(v);
                out[(size_t)r * ldo + n0 + wc * 64 + ct * 16 + lo] = *reinterpret_cast<bf16*>(&u);
            }
        }
    }
}

// ---------------------------------------------------------------------------
// CSR build: histogram, 3-stage parallel scan, fill edge list.
// ---------------------------------------------------------------------------
__global__ __launch_bounds__(256)
void hist_tgt(const int* __restrict__ edge, int* __restrict__ ecnt)
{
    const int e = blockIdx.x * blockDim.x + threadIdx.x;
    if (e >= NEDGE) return;
    atomicAdd(&ecnt[edge[2 * e]], 1);
}

__global__ __launch_bounds__(256)
void block_sums(const int* __restrict__ ecnt, int* __restrict__ bsum)
{
    __shared__ int red[256];
    const int t = threadIdx.x;
    const int idx = blockIdx.x * 256 + t;
    red[t] = (idx < NN) ? ecnt[idx] : 0;
    __syncthreads();
#pragma unroll
    for (int d = 128; d > 0; d >>= 1) {
        if (t < d) red[t] += red[t + d];
        __syncthreads();
    }
    if (t == 0) bsum[blockIdx.x] = red[0];
}

__global__ __launch_bounds__(256)
void scan_bsums(const int* __restrict__ bsum, int* __restrict__ bbase,
                int* __restrict__ off)
{
    __shared__ int s[256];
    const int t = threadIdx.x;
    s[t] = (t < SCAN_NBLK) ? bsum[t] : 0;
    __syncthreads();
    for (int d = 1; d < 256; d <<= 1) {
        const int v = (t >= d) ? s[t - d] : 0;
        __syncthreads();
        s[t] += v;
        __syncthreads();
    }
    if (t < SCAN_NBLK) bbase[t] = (t == 0) ? 0 : s[t - 1];
    if (t == 255) off[NN] = s[255];   // total = NEDGE
}

__global__ __launch_bounds__(256)
void block_scan(const int* __restrict__ ecnt, const int* __restrict__ bbase,
                int* __restrict__ off, int* __restrict__ cursor)
{
    __shared__ int s[256];
    const int t = threadIdx.x;
    const int idx = blockIdx.x * 256 + t;
    const int v = (idx < NN) ? ecnt[idx] : 0;
    s[t] = v;
    __syncthreads();
    for (int d = 1; d < 256; d <<= 1) {
        const int x = (t >= d) ? s[t - d] : 0;
        __syncthreads();
        s[t] += x;
        __syncthreads();
    }
    if (idx < NN) {
        const int excl = bbase[blockIdx.x] + s[t] - v;   // exclusive prefix
        off[idx] = excl;
        cursor[idx] = excl;
    }
}

__global__ __launch_bounds__(256)
void fill_elist(const int* __restrict__ edge,
                int* __restrict__ cursor, int* __restrict__ elist)
{
    const int e = blockIdx.x * blockDim.x + threadIdx.x;
    if (e >= NEDGE) return;
    const int tgt = edge[2 * e + 0];
    const int src = edge[2 * e + 1];
    const int pos = atomicAdd(&cursor[tgt], 1);
    elist[pos] = src;
}

// ---------------------------------------------------------------------------
// Atomic-free gather: dst[n,:] = sum_{j in off[n]..off[n+1]} h[elist[j],:]
// ---------------------------------------------------------------------------
__global__ __launch_bounds__(256)
void gather_nodes(const bf16* __restrict__ h,
                  const int* __restrict__ off,
                  const int* __restrict__ elist,
                  bf16* __restrict__ dst)
{
    const int node = blockIdx.x * 4 + (threadIdx.x >> 6);
    if (node >= NN) return;
    const int lane = threadIdx.x & 63;
    const int j0 = off[node];
    const int j1 = off[node + 1];

    float4 acc = make_float4(0.f, 0.f, 0.f, 0.f);
    for (int j = j0; j < j1; ++j) {
        const int src = elist[j];
        const ushort4 u = *reinterpret_cast<const ushort4*>(h + (size_t)src * HD + lane * 4);
        acc.x += bf2f(u.x);
        acc.y += bf2f(u.y);
        acc.z += bf2f(u.z);
        acc.w += bf2f(u.w);
    }
    ushort4 o;
    o.x = f2bf(acc.x); o.y = f2bf(acc.y); o.z = f2bf(acc.z); o.w = f2bf(acc.w);
    *reinterpret_cast<ushort4*>(dst + (size_t)node * ACT_LD + lane * 4) = o;
}

// ---------------------------------------------------------------------------
// post1 (256->1 dense + bn) fused with graph segment-sum (hierarchical).
// ---------------------------------------------------------------------------
__global__ __launch_bounds__(256)
void post1_segsum(const bf16* __restrict__ h,
                  const float* __restrict__ W,
                  const float* __restrict__ b,
                  const float* __restrict__ bn,
                  const int* __restrict__ seg,
                  float* __restrict__ outg)
{
    __shared__ float bins[NGRAPH];
    const int t = threadIdx.x;
    if (t < NGRAPH) bins[t] = 0.f;
    __syncthreads();

    const int wave = t >> 6;
    const int lane = t & 63;
    const float4 wv = *reinterpret_cast<const float4*>(W + lane * 4);
    const float g = bn[0], be = bn[1], mu = bn[2], va = bn[3];
    const float bscale = g * rsqrtf(va + BN_EPS);
    const float b0 = b[0];

    const int row0 = blockIdx.x * 64 + wave * 16;
#pragma unroll
    for (int i = 0; i < 16; ++i) {
        const int row = row0 + i;
        if (row >= NN) break;
        const ushort4 u = *reinterpret_cast<const ushort4*>(h + (size_t)row * HD + lane * 4);
        float s = bf2f(u.x) * wv.x + bf2f(u.y) * wv.y + bf2f(u.z) * wv.z + bf2f(u.w) * wv.w;
#pragma unroll
        for (int off = 32; off > 0; off >>= 1) s += __shfl_down(s, off);
        if (lane == 0) {
            const float y = bscale * (s + b0 - mu) + be;
            atomicAdd(&bins[seg[row]], y);
        }
    }
    __syncthreads();
    if (t < NGRAPH && bins[t] != 0.f) atomicAdd(&outg[t], bins[t]);
}

// ---------------------------------------------------------------------------
extern "C" void kernel_launch(void* const* d_in, const int* in_sizes, int n_in,
                              void* d_out, int out_size, void* d_ws, size_t ws_size,
                              hipStream_t stream)
{
    const float* x    = (const float*)d_in[0];
    const int*   edge = (const int*)d_in[1];
    const int*   seg  = (const int*)d_in[2];

    const float* Wsrc[7], *bi[7], *bnp[7], *ap[7];
    for (int L = 0; L < 7; ++L) {
        Wsrc[L] = (const float*)d_in[4 + 4 * L + 0];
        bi[L]   = (const float*)d_in[4 + 4 * L + 1];
        bnp[L]  = (const float*)d_in[4 + 4 * L + 2];
        ap[L]   = (const float*)d_in[4 + 4 * L + 3];
    }
    const float* post1_W  = (const float*)d_in[32];
    const float* post1_b  = (const float*)d_in[33];
    const float* post1_bn = (const float*)d_in[34];

    static const int Ks[7] = {128, 256, 256, 512, 768, 1024, 1280};

    // Workspace (~172 MB):
    bf16* act  = (bf16*)d_ws;                          // 128.0 MB
    bf16* h    = act + (size_t)NN * ACT_LD;            //  25.6 MB
    bf16* xb   = h + (size_t)NN * HD;                  //  12.8 MB
    bf16* wt0  = xb + (size_t)NN * 128;                //   2.16 MB total Wt
    bf16* WtB[7];
    {
        size_t o = 0;
        for (int L = 0; L < 7; ++L) { WtB[L] = wt0 + o; o += (size_t)Ks[L] * HD; }
    }
    int* ecnt   = (int*)(wt0 + (size_t)4224 * HD);
    int* off    = ecnt + NN;
    int* cursor = off + NN + 1;
    int* elist  = cursor + NN;
    int* bsum   = elist + NEDGE;
    int* bbase  = bsum + SCAN_NBLK;

    hipMemsetAsync(d_out, 0, (size_t)out_size * sizeof(float), stream);
    hipMemsetAsync(ecnt, 0, NN * sizeof(int), stream);

    const dim3 blk(256);
    const dim3 gemm_grid((NN + BM - 1) / BM, HD / BN);   // (391, 2)
    const int  edge_grid = (NEDGE + 255) / 256;
    const int  node_grid = (NN + 3) / 4;

    // weight transposes (fp32 KxH -> bf16 HxK) + x conversion
    for (int L = 0; L < 7; ++L)
        transpose_w<<<dim3(Ks[L] / 32, HD / 32), blk, 0, stream>>>(Wsrc[L], WtB[L], Ks[L]);
    convert_x<<<(NN * 32 + 255) / 256, blk, 0, stream>>>(x, xb);

    // CSR build (reused by all 4 gconv layers)
    hist_tgt<<<edge_grid, blk, 0, stream>>>(edge, ecnt);
    block_sums<<<SCAN_NBLK, blk, 0, stream>>>(ecnt, bsum);
    scan_bsums<<<1, blk, 0, stream>>>(bsum, bbase, off);
    block_scan<<<SCAN_NBLK, blk, 0, stream>>>(ecnt, bbase, off, cursor);
    fill_elist<<<edge_grid, blk, 0, stream>>>(edge, cursor, elist);

    // pre0: xb(K=128) -> h
    gemm_bn_act<<<gemm_grid, blk, 0, stream>>>(xb, 128, WtB[0], 128, bi[0], bnp[0], ap[0], h, HD, NN);
    // pre1: h(K=256) -> act[:,1024:1280) (= out1)
    gemm_bn_act<<<gemm_grid, blk, 0, stream>>>(h, HD, WtB[1], 256, bi[1], bnp[1], ap[1], act + 1024, ACT_LD, NN);

    // gconv layers: input = act cols [1024-256L, 1280), K = 256*(L+1)
    for (int L = 0; L < 4; ++L) {
        const int in_off = 1024 - 256 * L;
        const int K      = 256 * (L + 1);
        gemm_bn_act<<<gemm_grid, blk, 0, stream>>>(act + in_off, ACT_LD, WtB[2 + L], K, bi[2 + L], bnp[2 + L], ap[2 + L], h, HD, NN);
        gather_nodes<<<node_grid, blk, 0, stream>>>(h, off, elist, act + (in_off - 256));
    }

    // post0: act(K=1280) -> h
    gemm_bn_act<<<gemm_grid, blk, 0, stream>>>(act, ACT_LD, WtB[6], 1280, bi[6], bnp[6], ap[6], h, HD, NN);
    // post1 + segment-sum -> d_out (64 floats)
    post1_segsum<<<(NN + 63) / 64, blk, 0, stream>>>(h, post1_W, post1_b, post1_bn, seg, (float*)d_out);
}